// Round 1
// baseline (268.552 us; speedup 1.0000x reference)
//
#include <hip/hip_runtime.h>

#define AS1 __attribute__((address_space(1)))
#define AS3 __attribute__((address_space(3)))

typedef short short8 __attribute__((ext_vector_type(8)));
typedef float f32x16 __attribute__((ext_vector_type(16)));

// Problem constants
#define BATCH 4096
#define IN_F 256
#define OUT_F 256
#define HYP 128
#define HX 129            // HYP + 1 (b2g folded in as extra channel, gain 1.0)
#define KP (HX * IN_F)    // 33024 = big-GEMM K

__device__ __forceinline__ float bf2f(unsigned short u) {
  unsigned v = ((unsigned)u) << 16;
  float f;
  __builtin_memcpy(&f, &v, 4);
  return f;
}
__device__ __forceinline__ unsigned short f2bf(float f) {
  unsigned u;
  __builtin_memcpy(&u, &f, 4);
  unsigned r = u + 0x7fffu + ((u >> 16) & 1u);  // RTNE
  return (unsigned short)(r >> 16);
}

__device__ __forceinline__ void gld_lds16(const unsigned short* g, unsigned short* s) {
  __builtin_amdgcn_global_load_lds((const AS1 unsigned int*)g, (AS3 unsigned int*)s, 16, 0, 0);
}

// ---------------------------------------------------------------------------
// k_hidden: hg = relu(x@W1g + b1g) -> bf16 ; hb = relu(x@W1b + b1b) -> f32
//           also emits x in bf16. 8 batch rows per 256-thread block.
// ---------------------------------------------------------------------------
__global__ void k_hidden(const float* __restrict__ x,
                         const float* __restrict__ W1g, const float* __restrict__ b1g,
                         const float* __restrict__ W1b, const float* __restrict__ b1b,
                         unsigned short* __restrict__ hgb, float* __restrict__ hb,
                         unsigned short* __restrict__ xb) {
  __shared__ float xl[8 * IN_F];
  const int t = threadIdx.x;
  const int r0 = blockIdx.x * 8;
  for (int j0 = 0; j0 < 8 * IN_F; j0 += 256) {
    float v = x[r0 * IN_F + j0 + t];
    xl[j0 + t] = v;
    xb[r0 * IN_F + j0 + t] = f2bf(v);
  }
  __syncthreads();
  const int half = t >> 7;     // 0/1: which 4 rows
  const int h = t & 127;
  const int rb = half * 4;
  float ag[4] = {0.f, 0.f, 0.f, 0.f};
  float av[4] = {0.f, 0.f, 0.f, 0.f};
  for (int i = 0; i < IN_F; ++i) {
    const float wg = W1g[i * HYP + h];
    const float wb = W1b[i * HYP + h];
#pragma unroll
    for (int r = 0; r < 4; ++r) {
      const float xv = xl[(rb + r) * IN_F + i];
      ag[r] += xv * wg;
      av[r] += xv * wb;
    }
  }
  const float bg = b1g[h], bb = b1b[h];
#pragma unroll
  for (int r = 0; r < 4; ++r) {
    const int row = r0 + rb + r;
    float g = ag[r] + bg; g = g > 0.f ? g : 0.f;
    float v = av[r] + bb; v = v > 0.f ? v : 0.f;
    hgb[row * HYP + h] = f2bf(g);
    hb[row * HYP + h] = v;
  }
}

// ---------------------------------------------------------------------------
// k_bias: out[b,o] = b2b[o] + sum_h hb[b,h]*W2b[h,o]   (initializes d_out)
// ---------------------------------------------------------------------------
__global__ void k_bias(const float* __restrict__ hb, const float* __restrict__ W2b,
                       const float* __restrict__ b2b, float* __restrict__ out) {
  __shared__ float hl[8 * HYP];
  const int t = threadIdx.x;
  const int r0 = blockIdx.x * 8;
  for (int j0 = 0; j0 < 8 * HYP; j0 += 256) hl[j0 + t] = hb[r0 * HYP + j0 + t];
  __syncthreads();
  float acc[8] = {0.f, 0.f, 0.f, 0.f, 0.f, 0.f, 0.f, 0.f};
  for (int h = 0; h < HYP; ++h) {
    const float w = W2b[h * OUT_F + t];
#pragma unroll
    for (int r = 0; r < 8; ++r) acc[r] += hl[r * HYP + h] * w;
  }
  const float bo = b2b[t];
#pragma unroll
  for (int r = 0; r < 8; ++r) out[(r0 + r) * OUT_F + t] = acc[r] + bo;
}

// ---------------------------------------------------------------------------
// k_buildV: V[o][h*256+i] = bf16( h<128 ? W2g[h][o*256+i] : b2g[o*256+i] )
// One 16B chunk (8 elems) per thread; reads and writes both coalesced.
// ---------------------------------------------------------------------------
__global__ void k_buildV(const float* __restrict__ W2g, const float* __restrict__ b2g,
                         unsigned short* __restrict__ Vb) {
  const int cid = blockIdx.x * 256 + threadIdx.x;  // < 256*129*32
  const int ic = cid & 31;
  const int pair = cid >> 5;        // o*129 + h
  const int h = pair % HX;
  const int o = pair / HX;
  const float* src = (h < HYP) ? (W2g + (size_t)h * (OUT_F * IN_F) + o * IN_F + ic * 8)
                               : (b2g + o * IN_F + ic * 8);
  const float4 v0 = ((const float4*)src)[0];
  const float4 v1 = ((const float4*)src)[1];
  uint4 pk;
  pk.x = (unsigned)f2bf(v0.x) | ((unsigned)f2bf(v0.y) << 16);
  pk.y = (unsigned)f2bf(v0.z) | ((unsigned)f2bf(v0.w) << 16);
  pk.z = (unsigned)f2bf(v1.x) | ((unsigned)f2bf(v1.y) << 16);
  pk.w = (unsigned)f2bf(v1.z) | ((unsigned)f2bf(v1.w) << 16);
  *(uint4*)(Vb + (size_t)o * KP + h * IN_F + ic * 8) = pk;
}

// ---------------------------------------------------------------------------
// k_gemm: out[b,o] += sum_{h,i} hg[b,h]*x[b,i]*V[o][h*256+i]
// M-tile 128, N-tile 64, BK=64, mfma_f32_32x32x16_bf16.
// A synthesized: raw x fragments (preloaded, 64 VGPRs) accumulate into ah;
// hg scale applied to fp32 accumulator at h-group flush (linearity).
// B staged via global_load_lds w/ XOR chunk swizzle p = q^(n&7) (conflict-free).
// Grid (32, 4, 4): z = K-split of 129 BK-steps; fp32 atomicAdd epilogue.
// ---------------------------------------------------------------------------
__global__ __launch_bounds__(256, 2) void k_gemm(const unsigned short* __restrict__ Vb,
                                                 const unsigned short* __restrict__ hgb,
                                                 const unsigned short* __restrict__ xb,
                                                 float* __restrict__ out) {
  __shared__ __align__(16) unsigned short Bl[64 * 64];  // [o_local][k] rows of 128B, swizzled
  const int tid = threadIdx.x;
  const int lane = tid & 63;
  const int wave = tid >> 6;
  const int l31 = lane & 31;
  const int hi = lane >> 5;
  const int m0 = blockIdx.x * 128;
  const int o0 = blockIdx.y * 64;
  const int sBeg = blockIdx.z * 129;  // BK-steps; 516 total
  const int sEnd = sBeg + 129;
  const int mrow = m0 + wave * 32 + l31;  // this lane's A row

  // Preload all 16 x fragments of this row (k16-tile j covers i = j*16 + hi*8 .. +8)
  uint4 xf[16];
#pragma unroll
  for (int j = 0; j < 16; ++j)
    xf[j] = *(const uint4*)(xb + mrow * IN_F + j * 16 + hi * 8);

  f32x16 zv;
#pragma unroll
  for (int i = 0; i < 16; ++i) zv[i] = 0.0f;
  f32x16 acc0 = zv, acc1 = zv;  // hg-scaled accumulators (cols o0+l31, o0+32+l31)
  f32x16 ah0 = zv, ah1 = zv;    // per-h-group raw accumulators

  // staging: 512 chunks of 16B; thread stages chunks tid and tid+256
  const int L0 = tid, L1 = tid + 256;
  const int ro0 = L0 >> 3, rp0 = L0 & 7;
  const int ro1 = L1 >> 3, rp1 = L1 & 7;
  const unsigned short* vs0 = Vb + (size_t)(o0 + ro0) * KP + (size_t)((rp0 ^ (ro0 & 7)) * 8);
  const unsigned short* vs1 = Vb + (size_t)(o0 + ro1) * KP + (size_t)((rp1 ^ (ro1 & 7)) * 8);
  unsigned short* ls0 = &Bl[L0 * 8];
  unsigned short* ls1 = &Bl[L1 * 8];

  const int mw = m0 + wave * 32 + 4 * hi;  // C-layout base row for this lane

  int s = sBeg;
  while (s < sEnd) {
    const int h = s >> 2;
    const int ic0 = s & 3;
    const int remain = sEnd - s;
    float hgf[16];
    if (ic0 == 0 && remain >= 4) {
      // -------- full h-group: 4 BK-steps, constant xf indices --------
#pragma unroll
      for (int ic = 0; ic < 4; ++ic) {
        const int kofs = h * IN_F + ic * 64;
        __syncthreads();
        gld_lds16(vs0 + kofs, ls0);
        gld_lds16(vs1 + kofs, ls1);
        __builtin_amdgcn_s_waitcnt(0x0f70);  // vmcnt(0)
        __syncthreads();
        if (ic == 0) {
          // hg for flush; issued early, hidden under ~3 steps of MFMAs
          const int hm = (h < HYP) ? h : 0;
#pragma unroll
          for (int reg = 0; reg < 16; ++reg) {
            const int mloc = (reg & 3) + 8 * (reg >> 2);
            const unsigned short u = hgb[(size_t)(mw + mloc) * HYP + hm];
            hgf[reg] = (h < HYP) ? bf2f(u) : 1.0f;
          }
        }
#pragma unroll
        for (int t = 0; t < 4; ++t) {
          const short8 a = __builtin_bit_cast(short8, xf[ic * 4 + t]);
          const int q = t * 2 + hi;
          const int n1 = 32 + l31;
          const short8 b0 = *(const short8*)(&Bl[l31 * 64 + ((q ^ (l31 & 7)) * 8)]);
          const short8 b1 = *(const short8*)(&Bl[n1 * 64 + ((q ^ (n1 & 7)) * 8)]);
          ah0 = __builtin_amdgcn_mfma_f32_32x32x16_bf16(a, b0, ah0, 0, 0, 0);
          ah1 = __builtin_amdgcn_mfma_f32_32x32x16_bf16(a, b1, ah1, 0, 0, 0);
        }
      }
      s += 4;
    } else {
      // -------- partial h-group at split boundary (<=3 steps) --------
      {
        const int hm = (h < HYP) ? h : 0;
#pragma unroll
        for (int reg = 0; reg < 16; ++reg) {
          const int mloc = (reg & 3) + 8 * (reg >> 2);
          const unsigned short u = hgb[(size_t)(mw + mloc) * HYP + hm];
          hgf[reg] = (h < HYP) ? bf2f(u) : 1.0f;
        }
      }
      const int nIc = (4 - ic0 < remain) ? (4 - ic0) : remain;
      for (int ii = 0; ii < nIc; ++ii) {
        const int ic = ic0 + ii;
        const int kofs = h * IN_F + ic * 64;
        __syncthreads();
        gld_lds16(vs0 + kofs, ls0);
        gld_lds16(vs1 + kofs, ls1);
        __builtin_amdgcn_s_waitcnt(0x0f70);
        __syncthreads();
#pragma unroll
        for (int t = 0; t < 4; ++t) {
          const uint4 xv = *(const uint4*)(xb + mrow * IN_F + ic * 64 + t * 16 + hi * 8);
          const short8 a = __builtin_bit_cast(short8, xv);
          const int q = t * 2 + hi;
          const int n1 = 32 + l31;
          const short8 b0 = *(const short8*)(&Bl[l31 * 64 + ((q ^ (l31 & 7)) * 8)]);
          const short8 b1 = *(const short8*)(&Bl[n1 * 64 + ((q ^ (n1 & 7)) * 8)]);
          ah0 = __builtin_amdgcn_mfma_f32_32x32x16_bf16(a, b0, ah0, 0, 0, 0);
          ah1 = __builtin_amdgcn_mfma_f32_32x32x16_bf16(a, b1, ah1, 0, 0, 0);
        }
      }
      s += nIc;
    }
    // flush: acc += hg[m,h] * ah ; re-zero ah
#pragma unroll
    for (int reg = 0; reg < 16; ++reg) {
      acc0[reg] += hgf[reg] * ah0[reg];
      acc1[reg] += hgf[reg] * ah1[reg];
    }
    ah0 = zv;
    ah1 = zv;
  }

  // epilogue: atomic accumulate (4 K-splits per output)
#pragma unroll
  for (int reg = 0; reg < 16; ++reg) {
    const int row = mw + (reg & 3) + 8 * (reg >> 2);
    atomicAdd(&out[(size_t)row * OUT_F + o0 + l31], acc0[reg]);
    atomicAdd(&out[(size_t)row * OUT_F + o0 + 32 + l31], acc1[reg]);
  }
}

// ---------------------------------------------------------------------------
extern "C" void kernel_launch(void* const* d_in, const int* in_sizes, int n_in,
                              void* d_out, int out_size, void* d_ws, size_t ws_size,
                              hipStream_t stream) {
  const float* x = (const float*)d_in[0];
  const float* W1g = (const float*)d_in[1];
  const float* b1g = (const float*)d_in[2];
  const float* W2g = (const float*)d_in[3];
  const float* b2g = (const float*)d_in[4];
  const float* W1b = (const float*)d_in[5];
  const float* b1b = (const float*)d_in[6];
  const float* W2b = (const float*)d_in[7];
  const float* b2b = (const float*)d_in[8];
  float* out = (float*)d_out;

  char* ws = (char*)d_ws;
  const size_t szV = (size_t)OUT_F * KP * 2;        // 16,908,288
  const size_t szHg = (size_t)BATCH * HYP * 2;      //  1,048,576
  const size_t szXb = (size_t)BATCH * IN_F * 2;     //  2,097,152
  unsigned short* Vb = (unsigned short*)ws;
  unsigned short* hgb = (unsigned short*)(ws + szV);
  unsigned short* xb = (unsigned short*)(ws + szV + szHg);
  float* hb = (float*)(ws + szV + szHg + szXb);

  hipLaunchKernelGGL(k_buildV, dim3(OUT_F * HX / 8), dim3(256), 0, stream, W2g, b2g, Vb);
  hipLaunchKernelGGL(k_hidden, dim3(BATCH / 8), dim3(256), 0, stream,
                     x, W1g, b1g, W1b, b1b, hgb, hb, xb);
  hipLaunchKernelGGL(k_bias, dim3(BATCH / 8), dim3(256), 0, stream, hb, W2b, b2b, out);
  hipLaunchKernelGGL(k_gemm, dim3(BATCH / 128, OUT_F / 64, 4), dim3(256), 0, stream,
                     Vb, hgb, xb, out);
}

// Round 2
// 228.098 us; speedup vs baseline: 1.1774x; 1.1774x over previous
//
#include <hip/hip_runtime.h>

#define AS1 __attribute__((address_space(1)))
#define AS3 __attribute__((address_space(3)))

typedef short short8 __attribute__((ext_vector_type(8)));
typedef float f32x16 __attribute__((ext_vector_type(16)));
typedef unsigned short ushort4v __attribute__((ext_vector_type(4)));

// Problem constants
#define BATCH 4096
#define IN_F 256
#define OUT_F 256
#define HYP 128
#define HX 129            // HYP + 1 (b2g folded in as extra channel, gain 1.0)
#define KP (HX * IN_F)    // 33024 shorts per V row

__device__ __forceinline__ float bf2f(unsigned short u) {
  unsigned v = ((unsigned)u) << 16;
  float f;
  __builtin_memcpy(&f, &v, 4);
  return f;
}
__device__ __forceinline__ unsigned short f2bf(float f) {
  unsigned u;
  __builtin_memcpy(&u, &f, 4);
  unsigned r = u + 0x7fffu + ((u >> 16) & 1u);  // RTNE
  return (unsigned short)(r >> 16);
}

__device__ __forceinline__ void gld_lds16(const unsigned short* g, unsigned short* s) {
  __builtin_amdgcn_global_load_lds((const AS1 unsigned int*)g, (AS3 unsigned int*)s, 16, 0, 0);
}

// ---------------------------------------------------------------------------
// k_buildV: V[o][h*256+i] = bf16( h<128 ? W2g[h][o*256+i] : b2g[o*256+i] )
// ---------------------------------------------------------------------------
__global__ void k_buildV(const float* __restrict__ W2g, const float* __restrict__ b2g,
                         unsigned short* __restrict__ Vb) {
  const int cid = blockIdx.x * 256 + threadIdx.x;  // < 256*129*32
  const int ic = cid & 31;
  const int pair = cid >> 5;        // o*129 + h
  const int h = pair % HX;
  const int o = pair / HX;
  const float* src = (h < HYP) ? (W2g + (size_t)h * (OUT_F * IN_F) + o * IN_F + ic * 8)
                               : (b2g + o * IN_F + ic * 8);
  const float4 v0 = ((const float4*)src)[0];
  const float4 v1 = ((const float4*)src)[1];
  uint4 pk;
  pk.x = (unsigned)f2bf(v0.x) | ((unsigned)f2bf(v0.y) << 16);
  pk.y = (unsigned)f2bf(v0.z) | ((unsigned)f2bf(v0.w) << 16);
  pk.z = (unsigned)f2bf(v1.x) | ((unsigned)f2bf(v1.y) << 16);
  pk.w = (unsigned)f2bf(v1.z) | ((unsigned)f2bf(v1.w) << 16);
  *(uint4*)(Vb + (size_t)o * KP + h * IN_F + ic * 8) = pk;
}

// ---------------------------------------------------------------------------
// k_pre: fused hidden (hg bf16 transposed [h][b], hb) + bias GEMM (out init)
//        + x -> bf16. 16 batch rows per 256-thread block.
// ---------------------------------------------------------------------------
__global__ __launch_bounds__(256) void k_pre(const float* __restrict__ x,
                                             const float* __restrict__ W1g, const float* __restrict__ b1g,
                                             const float* __restrict__ W1b, const float* __restrict__ b1b,
                                             const float* __restrict__ W2b, const float* __restrict__ b2b,
                                             unsigned short* __restrict__ hgbT,
                                             unsigned short* __restrict__ xb,
                                             float* __restrict__ out) {
  __shared__ float xl[16 * IN_F];                 // 16 KB
  __shared__ float hbl[16 * HYP];                 // 8 KB  [row][h]
  __shared__ unsigned short hgt[HYP * 16];        // 4 KB  [h][row]
  const int t = threadIdx.x;
  const int r0 = blockIdx.x * 16;
  for (int j0 = 0; j0 < 16 * IN_F; j0 += 256) {
    const float v = x[(size_t)r0 * IN_F + j0 + t];
    xl[j0 + t] = v;
    xb[(size_t)r0 * IN_F + j0 + t] = f2bf(v);
  }
  __syncthreads();
  const int h = t & 127;
  const int rb = (t >> 7) * 8;
  float ag[8] = {0.f, 0.f, 0.f, 0.f, 0.f, 0.f, 0.f, 0.f};
  float av[8] = {0.f, 0.f, 0.f, 0.f, 0.f, 0.f, 0.f, 0.f};
  for (int i = 0; i < IN_F; ++i) {
    const float wg = W1g[i * HYP + h];
    const float wb = W1b[i * HYP + h];
#pragma unroll
    for (int r = 0; r < 8; ++r) {
      const float xv = xl[(rb + r) * IN_F + i];
      ag[r] += xv * wg;
      av[r] += xv * wb;
    }
  }
  const float bg = b1g[h], bb = b1b[h];
#pragma unroll
  for (int r = 0; r < 8; ++r) {
    float g = ag[r] + bg; g = g > 0.f ? g : 0.f;
    float v = av[r] + bb; v = v > 0.f ? v : 0.f;
    hgt[h * 16 + rb + r] = f2bf(g);
    hbl[(rb + r) * HYP + h] = v;
  }
  __syncthreads();
  // coalesced-ish transposed store: hgbT[h][r0..r0+16)
  {
    const int h2 = t >> 1, part = t & 1;
    const uint4 pk = *(const uint4*)&hgt[h2 * 16 + part * 8];
    *(uint4*)&hgbT[(size_t)h2 * BATCH + r0 + part * 8] = pk;
  }
  // out init: out[r0+r][o=t] = b2b + sum_h hb*W2b
  float acc[16];
#pragma unroll
  for (int r = 0; r < 16; ++r) acc[r] = 0.f;
  for (int hh = 0; hh < HYP; ++hh) {
    const float w = W2b[hh * OUT_F + t];
#pragma unroll
    for (int r = 0; r < 16; ++r) acc[r] += hbl[r * HYP + hh] * w;
  }
  const float bo = b2b[t];
#pragma unroll
  for (int r = 0; r < 16; ++r) out[(size_t)(r0 + r) * OUT_F + t] = acc[r] + bo;
}

// ---------------------------------------------------------------------------
// k_gemm: out[b,o] += sum_h hg[b,h] * (sum_i V[o][h*256+i]*x[b,i])
// M-tile 256 (4 waves x 64 rows), N-tile 64, round = full h-group (K=256).
// Double-buffered 32KB LDS B-tiles staged via global_load_lds width=16,
// issued one round ahead (latency hidden under 64 MFMAs/wave/round).
// XOR chunk swizzle (pos = chunk ^ (row&7)) on 16B chunks within rows.
// hg scales pre-staged in LDS; applied to fp32 accum at h-group flush.
// Grid (16,4,4): z = h-range split; fp32 atomicAdd epilogue.
// ---------------------------------------------------------------------------
__global__ __launch_bounds__(256, 1) void k_gemm(const unsigned short* __restrict__ Vb,
                                                 const unsigned short* __restrict__ hgbT,
                                                 const unsigned short* __restrict__ xb,
                                                 float* __restrict__ out) {
  __shared__ __align__(16) unsigned short Bl[2][64 * 256];   // 2 x 32 KB
  __shared__ __align__(16) unsigned short hgs[33 * 256];     // 16.9 KB [h_local][m]
  const int tid = threadIdx.x;
  const int lane = tid & 63;
  const int wave = tid >> 6;
  const int l31 = lane & 31;
  const int hi = lane >> 5;
  const int m0 = blockIdx.x * 256;
  const int o0 = blockIdx.y * 64;
  const int z = blockIdx.z;
  const int hBeg = (z * HX) >> 2;
  const int hEnd = ((z + 1) * HX) >> 2;
  const int nh = hEnd - hBeg;   // 32,32,32,33

  // ---- stage hg tile [h_local][m] (h==128 -> 1.0) ----
  for (int idx = tid; idx < nh * 256; idx += 256) {
    const int hl = idx >> 8;
    const int hh = hBeg + hl;
    hgs[idx] = (hh == HYP) ? (unsigned short)0x3F80
                           : hgbT[(size_t)hh * BATCH + m0 + (idx & 255)];
  }

  // ---- preload A fragments (2 m-subtiles x 16 k16-tiles) ----
  const int mrow0 = m0 + wave * 64 + l31;
  const int mrow1 = mrow0 + 32;
  uint4 xf0[16], xf1[16];
#pragma unroll
  for (int j = 0; j < 16; ++j) {
    xf0[j] = *(const uint4*)(xb + (size_t)mrow0 * IN_F + j * 16 + hi * 8);
    xf1[j] = *(const uint4*)(xb + (size_t)mrow1 * IN_F + j * 16 + hi * 8);
  }

  // ---- staging geometry: 2048 chunks of 16B per round, 8 per thread ----
  const int nB = tid >> 5;            // base row (rows nB + 8j)
  const int p = tid & 31;             // stored position within row
  const int cs = p ^ (nB & 7);        // source chunk (XOR swizzle, self-inverse)
  const unsigned short* gsrc = Vb + (size_t)(o0 + nB) * KP + cs * 8 + (size_t)hBeg * IN_F;

  f32x16 zv;
#pragma unroll
  for (int i = 0; i < 16; ++i) zv[i] = 0.0f;
  f32x16 acc00 = zv, acc01 = zv, acc10 = zv, acc11 = zv;
  f32x16 ah00 = zv, ah01 = zv, ah10 = zv, ah11 = zv;

  // prologue: stage round 0 into buf 0
#pragma unroll
  for (int j = 0; j < 8; ++j)
    gld_lds16(gsrc + (size_t)j * 8 * KP, &Bl[0][(tid + 256 * j) * 8]);
  __syncthreads();

  for (int r = 0; r < nh; ++r) {
    const int buf = r & 1;
    if (r + 1 < nh) {  // issue next round's staging ahead of compute
      const unsigned short* gs = gsrc + (size_t)(r + 1) * IN_F;
#pragma unroll
      for (int j = 0; j < 8; ++j)
        gld_lds16(gs + (size_t)j * 8 * KP, &Bl[buf ^ 1][(tid + 256 * j) * 8]);
    }
    // hg scales for this h (broadcast LDS reads)
    float hgf0[16], hgf1[16];
#pragma unroll
    for (int q = 0; q < 4; ++q) {
      const ushort4v v0 = *(const ushort4v*)&hgs[r * 256 + wave * 64 + 4 * hi + q * 8];
      const ushort4v v1 = *(const ushort4v*)&hgs[r * 256 + wave * 64 + 32 + 4 * hi + q * 8];
#pragma unroll
      for (int e = 0; e < 4; ++e) {
        hgf0[q * 4 + e] = bf2f(v0[e]);
        hgf1[q * 4 + e] = bf2f(v1[e]);
      }
    }
    const unsigned short* bp = &Bl[buf][0];
#pragma unroll
    for (int ic = 0; ic < 4; ++ic) {
#pragma unroll
      for (int t = 0; t < 4; ++t) {
        const int c0 = ic * 8 + t * 2 + hi;
        const int pr = c0 ^ (l31 & 7);
        const short8 b0 = *(const short8*)(bp + l31 * 256 + pr * 8);
        const short8 b1 = *(const short8*)(bp + (32 + l31) * 256 + pr * 8);
        const short8 a0 = __builtin_bit_cast(short8, xf0[ic * 4 + t]);
        const short8 a1 = __builtin_bit_cast(short8, xf1[ic * 4 + t]);
        ah00 = __builtin_amdgcn_mfma_f32_32x32x16_bf16(a0, b0, ah00, 0, 0, 0);
        ah01 = __builtin_amdgcn_mfma_f32_32x32x16_bf16(a0, b1, ah01, 0, 0, 0);
        ah10 = __builtin_amdgcn_mfma_f32_32x32x16_bf16(a1, b0, ah10, 0, 0, 0);
        ah11 = __builtin_amdgcn_mfma_f32_32x32x16_bf16(a1, b1, ah11, 0, 0, 0);
      }
    }
    // flush: acc += hg * ah (linearity: hg scale applied post-MFMA)
#pragma unroll
    for (int g = 0; g < 16; ++g) {
      acc00[g] += hgf0[g] * ah00[g];
      acc01[g] += hgf0[g] * ah01[g];
      acc10[g] += hgf1[g] * ah10[g];
      acc11[g] += hgf1[g] * ah11[g];
    }
    ah00 = zv; ah01 = zv; ah10 = zv; ah11 = zv;
    __syncthreads();  // drains next-buf loads (issued ~2000 cyc ago) + guards buf reuse
  }

  // epilogue: atomic accumulate (4 h-splits per output)
  const int mb = m0 + wave * 64 + 4 * hi;
#pragma unroll
  for (int g = 0; g < 16; ++g) {
    const int row0 = mb + (g & 3) + 8 * (g >> 2);
    atomicAdd(&out[(size_t)row0 * OUT_F + o0 + l31], acc00[g]);
    atomicAdd(&out[(size_t)row0 * OUT_F + o0 + 32 + l31], acc01[g]);
    atomicAdd(&out[(size_t)(row0 + 32) * OUT_F + o0 + l31], acc10[g]);
    atomicAdd(&out[(size_t)(row0 + 32) * OUT_F + o0 + 32 + l31], acc11[g]);
  }
}

// ---------------------------------------------------------------------------
extern "C" void kernel_launch(void* const* d_in, const int* in_sizes, int n_in,
                              void* d_out, int out_size, void* d_ws, size_t ws_size,
                              hipStream_t stream) {
  const float* x = (const float*)d_in[0];
  const float* W1g = (const float*)d_in[1];
  const float* b1g = (const float*)d_in[2];
  const float* W2g = (const float*)d_in[3];
  const float* b2g = (const float*)d_in[4];
  const float* W1b = (const float*)d_in[5];
  const float* b1b = (const float*)d_in[6];
  const float* W2b = (const float*)d_in[7];
  const float* b2b = (const float*)d_in[8];
  float* out = (float*)d_out;

  char* ws = (char*)d_ws;
  const size_t szV = (size_t)OUT_F * KP * 2;        // 16,908,288
  const size_t szHg = (size_t)HYP * BATCH * 2;      //  1,048,576
  unsigned short* Vb = (unsigned short*)ws;
  unsigned short* hgbT = (unsigned short*)(ws + szV);
  unsigned short* xb = (unsigned short*)(ws + szV + szHg);

  hipLaunchKernelGGL(k_buildV, dim3(OUT_F * HX / 8), dim3(256), 0, stream, W2g, b2g, Vb);
  hipLaunchKernelGGL(k_pre, dim3(BATCH / 16), dim3(256), 0, stream,
                     x, W1g, b1g, W1b, b1b, W2b, b2b, hgbT, xb, out);
  hipLaunchKernelGGL(k_gemm, dim3(BATCH / 256, OUT_F / 64, 4), dim3(256), 0, stream,
                     Vb, hgbT, xb, out);
}